// Round 15
// baseline (16.608 us; speedup 1.0000x reference)
//
#include <hip/hip_runtime.h>
#include <math.h>

// ECT layer: ect[b,t,r] = sum_{n: batch[n]==b} sigmoid(8*(lin[r] - <x_n,v_t>))
// N=100000, D=3, T=64, R=64, B=128, lin = linspace(-1.1,1.1,64), d = 2.2/63.
//
// Validated core: CIC-deposit nh onto lin-aligned grid (pad 63 below, bins
// 63..221 at scale 256), convolve with compile-time sigmoid taps (literal
// fmas + ds_read2); 64 saturated taps folded into a register suffix-scan
// window. r7: u32 LDS atomics (f32 LDS atomics = slow serial FP-RMW path on
// gfx950: 4x). r11: every extra dispatch costs ~3-5us -> single dispatch.
// r13/r14: 16-bit-packed u32 atomics + integer bin math (fewer DS bytes,
// ~12 VALU/deposit).
//
// Round-15: TPB 4->8, TQ 16->8 (1024 blocks, still 8 blocks/CU, 16KB LDS).
// Total deposit/conv/scan work invariant, but per-cloud redundancy halves:
// x-segment reads 16x -> 8x, binary-search chains 4096 -> 2048. Deposit
// address is now fully OR-folded: He region = 4096B exactly, so parity
// select = bit 12 = (ufix&256)<<4, row base = t_l<<9; wbyte = or3. Each
// wave owns 2 rows in reconstruct/scan/conv (statically unrolled).

#define THREADS 256
#define TPB 8              // directions per block
#define TQ  8              // blocks per point cloud: TPB*TQ = 64
#define J0  64             // taps j<J0 == 1.0 exactly (window via scan)
#define STEPS 144          // real taps j in [J0,STEPS): 80 literal fmas
#define ROWW 128           // u32 words per row per parity array
#define HO_BASE (TPB * ROWW)            // Ho offset in u32 words (1024)
#define HF_BASE (2 * TPB * ROWW)        // f32 H region offset (2048)
#define ROW32 256          // f32 elements per row in conv buffer
#define BSEG 128

#if __has_builtin(__builtin_amdgcn_fmed3f)
#define CLAMP(v, lo, hi) __builtin_amdgcn_fmed3f((v), (lo), (hi))
#else
#define CLAMP(v, lo, hi) fminf(fmaxf((v), (lo)), (hi))
#endif

// ---- compile-time sigmoid tap table (folds the 2^-8 quanta unscale) ----
constexpr double cexp_taylor(double r) {
    double s = 1.0, term = 1.0;
    for (int i = 1; i < 18; ++i) { term *= r / (double)i; s += term; }
    return s;
}
constexpr double cexp(double x) {
    const double LN2 = 0.69314718055994530942;
    const int n = (int)(x / LN2 + (x >= 0.0 ? 0.5 : -0.5));
    const double r = x - (double)n * LN2;
    double e = cexp_taylor(r);
    if (n >= 0) { for (int i = 0; i < n;  ++i) e *= 2.0; }
    else        { for (int i = 0; i < -n; ++i) e *= 0.5; }
    return e;
}
struct WTab {
    float w[STEPS];
    constexpr WTab() : w() {
        const double d = 2.2 / 63.0;
        for (int j = 0; j < STEPS; ++j) {
            const double z = 8.0 * d * (double)(111 - j);
            w[j] = (float)(1.0 / ((1.0 + cexp(-z)) * 256.0));
        }
    }
};
constexpr WTab WT;

// inclusive suffix sum within a 64-lane wave
__device__ __forceinline__ float wave_suffix(float x, int lane) {
#pragma unroll
    for (int d = 1; d < 64; d <<= 1) {
        const float y = __shfl_down(x, d, 64);
        x += (lane + d < 64) ? y : 0.0f;
    }
    return x;
}

// uniform scalar lower_bound, +-1024 window around expected position
// (validated by 2 loads; falls back to [0,n) -> unconditionally correct)
__device__ __forceinline__ int lower_scalar(const int* __restrict__ A, int n,
                                            int val) {
    const long long g = ((long long)val * (long long)n) >> 7;
    int lo = (int)(g - 1024 > 0 ? g - 1024 : 0);
    int hi = (int)(g + 1024 < n ? g + 1024 : n);
    const bool okl = (lo == 0) || (A[__builtin_amdgcn_readfirstlane(lo - 1)] < val);
    const bool okh = (hi == n) || (A[__builtin_amdgcn_readfirstlane(hi)] >= val);
    if (!(okl && okh)) { lo = 0; hi = n; }
    while (hi > lo) {
        const int mid = (lo + hi) >> 1;
        const int key = A[__builtin_amdgcn_readfirstlane(mid)];
        if (key < val) lo = mid + 1; else hi = mid;
    }
    return lo;
}

__global__ __launch_bounds__(THREADS, 8) void ect_fused12_kernel(
    const float* __restrict__ x,      // [N,3]
    const float* __restrict__ v,      // [3,64]
    const int*   __restrict__ batch,  // [N] sorted 0..127
    float* __restrict__ out,          // [128,64,64]
    int n, float inv_d256, float bias256)
{
    // [He: 1024 u32 = 4096 B][Ho: 1024 u32][Hf: 2048 f32] = 16 KiB
    __shared__ unsigned Ls[2 * TPB * ROWW + TPB * ROW32];

    const int tid  = threadIdx.x;
    const int wv   = tid >> 6;
    const int lane = tid & 63;
    const int b    = blockIdx.x >> 3;            // / TQ
    const int tq   = blockIdx.x & (TQ - 1);

    // zero the packed histograms (2048 u32 = 8KB; Hf overwritten later)
    {
        unsigned long long* z = (unsigned long long*)Ls;
        for (int i = tid; i < TPB * ROWW; i += THREADS) z[i] = 0ull;
    }

    // segment bounds: two scalar s_load chains, overlapped with zeroing
    const int s0 = lower_scalar(batch, n, b);
    const int s1 = lower_scalar(batch, n, b + 1);

    // deposit mapping: lane = (t_l 0..7, slot 0..7); block = 32 nodes/iter
    const int t_l  = lane >> 3;
    const int slot = (lane & 7) + (wv << 3);     // 0..31 across waves
    const int tbase = tq * TPB;
    const int t    = tbase + t_l;
    const float va = v[t], vb = v[64 + t], vc = v[128 + t];
    const int rowbyte = t_l << 9;                // t_l * 512 B (bits 9..11)

    __syncthreads();                             // barrier 1: zero done

    // deposit one (node,dir): ~12 VALU + 1 ds_add_u32.
    // a = ufix>>8 in [63,221]; (a,a+1) pair -> even a: He[a>>1], odd: Ho[a>>1].
    // wbyte OR-folds: bin word (bits 2..8) | parity->Ho (bit 12) | row (9..11).
#define DEPOSIT(x0, x1, x2)                                                   \
    {                                                                         \
        const float nh = fmaf((x0), va, fmaf((x1), vb, (x2) * vc));           \
        float bf = fmaf(nh, inv_d256, bias256);                               \
        bf = CLAMP(bf, 16128.0f, 56831.0f);      /* a in [63, 221] */         \
        const unsigned ufix = (unsigned)bf;                                   \
        const unsigned q1   = ufix & 255u;                                    \
        const unsigned val  = (q1 << 16) + (256u - q1);                       \
        const unsigned wbyte = ((ufix >> 7) & ~3u)                            \
                             | ((ufix & 256u) << 4)                           \
                             | (unsigned)rowbyte;                             \
        atomicAdd((unsigned*)((char*)Ls + wbyte), val);                       \
    }

    // ---- phase 1: CIC deposit; full 128-node chunks guard-free + tail ----
    {
        const int len = s1 - s0;
        const int nfull = len >> 7;
        int base = s0;
        for (int c = 0; c < nfull; ++c, base += 128) {
            float xs[4][3];
#pragma unroll
            for (int k = 0; k < 4; ++k) {
                const float3 xx = *(const float3*)(x + 3 * (size_t)(base + (k << 5) + slot));
                xs[k][0] = xx.x; xs[k][1] = xx.y; xs[k][2] = xx.z;
            }
#pragma unroll
            for (int k = 0; k < 4; ++k) DEPOSIT(xs[k][0], xs[k][1], xs[k][2]);
        }
        for (; base < s1; base += 32) {
            const int idx = base + slot;
            if (idx < s1) {
                const float3 xx = *(const float3*)(x + 3 * (size_t)idx);
                DEPOSIT(xx.x, xx.y, xx.z);
            }
        }
    }

    __syncthreads();                             // barrier 2: deposits done

    // ---- per-wave rows 2wv, 2wv+1: reconstruct -> scan -> (barrier) conv ----
    // H[a] = He.half[a] + Ho.half[a-1]:
    //   a even: He[a>>1].lo + (a>0 ? Ho[(a>>1)-1].hi : 0)
    //   a odd : Ho[a>>1].lo + He[a>>1].hi
    float win[2];
    {
        const int par = lane & 1;
#pragma unroll
        for (int rr = 0; rr < 2; ++rr) {
            const int row = 2 * wv + rr;
            const unsigned* He = Ls + row * ROWW;
            const unsigned* Ho = Ls + HO_BASE + row * ROWW;
            float* Hf = (float*)(Ls + HF_BASE) + row * ROW32;
            float c0, c1, c2, c3;
            {
                unsigned heW, he, ho;
                // q = 0
                heW = He[lane >> 1];
                he  = par ? (heW >> 16) : (heW & 0xFFFFu);
                ho  = 0u;
                if (lane > 0) {
                    const unsigned hoW = Ho[(lane - 1) >> 1];
                    ho = par ? (hoW & 0xFFFFu) : (hoW >> 16);
                }
                c0 = (float)(he + ho);
                // q = 1..3 (a = lane + 64q > 0 always)
                const int a1 = lane + 64, a2 = lane + 128, a3 = lane + 192;
                heW = He[a1 >> 1]; he = par ? (heW >> 16) : (heW & 0xFFFFu);
                { const unsigned hoW = Ho[(a1 - 1) >> 1];
                  ho = par ? (hoW & 0xFFFFu) : (hoW >> 16); }
                c1 = (float)(he + ho); Hf[a1] = c1;
                heW = He[a2 >> 1]; he = par ? (heW >> 16) : (heW & 0xFFFFu);
                { const unsigned hoW = Ho[(a2 - 1) >> 1];
                  ho = par ? (hoW & 0xFFFFu) : (hoW >> 16); }
                c2 = (float)(he + ho); Hf[a2] = c2;
                heW = He[a3 >> 1]; he = par ? (heW >> 16) : (heW & 0xFFFFu);
                { const unsigned hoW = Ho[(a3 - 1) >> 1];
                  ho = par ? (hoW & 0xFFFFu) : (hoW >> 16); }
                c3 = (float)(he + ho); Hf[a3] = c3;
            }
            // register suffix scan; 64-tap saturated window in-register
            float tot23 = c2 + c3;
#pragma unroll
            for (int d = 1; d < 64; d <<= 1) tot23 += __shfl_xor(tot23, d, 64);
            const float s1v   = wave_suffix(c1, lane) + tot23;
            const float carry = __shfl(s1v, 0, 64);
            const float s0v   = wave_suffix(c0, lane) + carry;
            win[rr] = (s0v - s1v) * (1.0f / 256.0f);
        }
    }

    __syncthreads();   // barrier 3: Hf visible to cross-lane conv reads

    // ---- phase 2: conv, 80 literal-fma taps per row, 40 ds_read2 ----
#pragma unroll
    for (int rr = 0; rr < 2; ++rr) {
        const int row = 2 * wv + rr;
        const float* H = (const float*)(Ls + HF_BASE) + row * ROW32 + lane;
        float a0 = win[rr], a1 = 0.f;
#pragma unroll
        for (int j = J0; j < STEPS; j += 2) {
            a0 = fmaf(WT.w[j],     H[j],     a0);
            a1 = fmaf(WT.w[j + 1], H[j + 1], a1);
        }
        out[((size_t)b * 64 + tbase + row) * 64 + lane] = a0 + a1;
    }
#undef DEPOSIT
}

extern "C" void kernel_launch(void* const* d_in, const int* in_sizes, int n_in,
                              void* d_out, int out_size, void* d_ws, size_t ws_size,
                              hipStream_t stream) {
    const float* x     = (const float*)d_in[0];
    const float* v     = (const float*)d_in[1];
    const int*   batch = (const int*)d_in[2];
    float*       out   = (float*)d_out;

    const int n = in_sizes[0] / 3;

    const double d = 2.2 / 63.0;
    const float inv_d256 = (float)(256.0 / d);         // bin scale 256
    const float bias256  = (79.5f + 63.0f) * 256.0f;   // 36480: pad included

    hipLaunchKernelGGL(ect_fused12_kernel, dim3(BSEG * TQ), dim3(THREADS), 0,
                       stream, x, v, batch, out, n, inv_d256, bias256);
}

// Round 16
// 16.431 us; speedup vs baseline: 1.0108x; 1.0108x over previous
//
#include <hip/hip_runtime.h>
#include <math.h>

// ECT layer: ect[b,t,r] = sum_{n: batch[n]==b} sigmoid(8*(lin[r] - <x_n,v_t>))
// N=100000, D=3, T=64, R=64, B=128, lin = linspace(-1.1,1.1,64), d = 2.2/63.
//
// Validated core: CIC-deposit nh onto lin-aligned grid (pad 63 below, bins
// 63..221 at scale 256), convolve with compile-time sigmoid taps (literal
// fmas + ds_read2); 64 saturated taps folded into a register suffix-scan
// window. r7: u32 LDS atomics (f32 LDS atomics = slow serial FP-RMW path on
// gfx950: 4x). r11: extra dispatches cost ~3-5us -> single dispatch.
// r13/r14: 16-bit-packed u32 atomics + integer bin math.
//
// Round-16: DS-pipe model says deposit atomics + conv reads + scan shfls sum
// to the wall, and the biggest avoidable term is deposit BANK CONFLICT:
// ROWW=128 => row stride == 0 mod 32 banks, so all 8 direction rows alias
// onto the same bank set and Gaussian-clustered bins stack ~4-8 RMW turns
// per bank per atomic instruction. Fix (only change this round):
//   - row stride 132 words (528 B): rows shift banks by 4*t_l -> 8 rows
//     cover all 32 banks evenly.
//   - Ho region at word 1072 (== 16 mod 32): odd-parity array 16 banks off
//     the even one, so adjacent-bin (He vs Ho) deposits don't collide.
//   - deposit address is add-based (rowbyte = t_l*528; parity sel 4288).

#define THREADS 256
#define TPB 8              // directions per block
#define TQ  8              // blocks per point cloud: TPB*TQ = 64
#define J0  64             // taps j<J0 == 1.0 exactly (window via scan)
#define STEPS 144          // real taps j in [J0,STEPS): 80 literal fmas
#define ROWW 132           // u32 words per row per parity array (stagger!)
#define HO_BASEW 1072      // Ho offset in u32 words: 8*132=1056 +16 pad
#define HF_BASEW 2128      // f32 H region offset in words: 1072+1056
#define ROW32 256          // f32 elements per row in conv buffer
#define BSEG 128

#if __has_builtin(__builtin_amdgcn_fmed3f)
#define CLAMP(v, lo, hi) __builtin_amdgcn_fmed3f((v), (lo), (hi))
#else
#define CLAMP(v, lo, hi) fminf(fmaxf((v), (lo)), (hi))
#endif

// ---- compile-time sigmoid tap table (folds the 2^-8 quanta unscale) ----
constexpr double cexp_taylor(double r) {
    double s = 1.0, term = 1.0;
    for (int i = 1; i < 18; ++i) { term *= r / (double)i; s += term; }
    return s;
}
constexpr double cexp(double x) {
    const double LN2 = 0.69314718055994530942;
    const int n = (int)(x / LN2 + (x >= 0.0 ? 0.5 : -0.5));
    const double r = x - (double)n * LN2;
    double e = cexp_taylor(r);
    if (n >= 0) { for (int i = 0; i < n;  ++i) e *= 2.0; }
    else        { for (int i = 0; i < -n; ++i) e *= 0.5; }
    return e;
}
struct WTab {
    float w[STEPS];
    constexpr WTab() : w() {
        const double d = 2.2 / 63.0;
        for (int j = 0; j < STEPS; ++j) {
            const double z = 8.0 * d * (double)(111 - j);
            w[j] = (float)(1.0 / ((1.0 + cexp(-z)) * 256.0));
        }
    }
};
constexpr WTab WT;

// inclusive suffix sum within a 64-lane wave
__device__ __forceinline__ float wave_suffix(float x, int lane) {
#pragma unroll
    for (int d = 1; d < 64; d <<= 1) {
        const float y = __shfl_down(x, d, 64);
        x += (lane + d < 64) ? y : 0.0f;
    }
    return x;
}

// uniform scalar lower_bound, +-1024 window around expected position
// (validated by 2 loads; falls back to [0,n) -> unconditionally correct)
__device__ __forceinline__ int lower_scalar(const int* __restrict__ A, int n,
                                            int val) {
    const long long g = ((long long)val * (long long)n) >> 7;
    int lo = (int)(g - 1024 > 0 ? g - 1024 : 0);
    int hi = (int)(g + 1024 < n ? g + 1024 : n);
    const bool okl = (lo == 0) || (A[__builtin_amdgcn_readfirstlane(lo - 1)] < val);
    const bool okh = (hi == n) || (A[__builtin_amdgcn_readfirstlane(hi)] >= val);
    if (!(okl && okh)) { lo = 0; hi = n; }
    while (hi > lo) {
        const int mid = (lo + hi) >> 1;
        const int key = A[__builtin_amdgcn_readfirstlane(mid)];
        if (key < val) lo = mid + 1; else hi = mid;
    }
    return lo;
}

__global__ __launch_bounds__(THREADS, 8) void ect_fused13_kernel(
    const float* __restrict__ x,      // [N,3]
    const float* __restrict__ v,      // [3,64]
    const int*   __restrict__ batch,  // [N] sorted 0..127
    float* __restrict__ out,          // [128,64,64]
    int n, float inv_d256, float bias256)
{
    // [He: 8x132 u32][pad 16][Ho: 8x132 u32][Hf: 8x256 f32] = 16704 B
    __shared__ unsigned Ls[HF_BASEW + TPB * ROW32];

    const int tid  = threadIdx.x;
    const int wv   = tid >> 6;
    const int lane = tid & 63;
    const int b    = blockIdx.x >> 3;            // / TQ
    const int tq   = blockIdx.x & (TQ - 1);

    // zero the packed histograms (+pad): 2128 words = 1064 u64
    {
        unsigned long long* z = (unsigned long long*)Ls;
        for (int i = tid; i < HF_BASEW / 2; i += THREADS) z[i] = 0ull;
    }

    // segment bounds: two scalar s_load chains, overlapped with zeroing
    const int s0 = lower_scalar(batch, n, b);
    const int s1 = lower_scalar(batch, n, b + 1);

    // deposit mapping: lane = (t_l 0..7, slot 0..7); block = 32 nodes/iter
    const int t_l  = lane >> 3;
    const int slot = (lane & 7) + (wv << 3);     // 0..31 across waves
    const int tbase = tq * TPB;
    const int t    = tbase + t_l;
    const float va = v[t], vb = v[64 + t], vc = v[128 + t];
    const int rowbyte = t_l * 528;               // staggered row base (bytes)

    __syncthreads();                             // barrier 1: zero done

    // deposit one (node,dir): ~13 VALU + 1 ds_add_u32.
    // a = ufix>>8 in [63,221]; (a,a+1): even a -> He[a>>1], odd -> Ho[a>>1].
#define DEPOSIT(x0, x1, x2)                                                   \
    {                                                                         \
        const float nh = fmaf((x0), va, fmaf((x1), vb, (x2) * vc));           \
        float bf = fmaf(nh, inv_d256, bias256);                               \
        bf = CLAMP(bf, 16128.0f, 56831.0f);      /* a in [63, 221] */         \
        const unsigned ufix = (unsigned)bf;                                   \
        const unsigned q1   = ufix & 255u;                                    \
        const unsigned val  = (q1 << 16) + (256u - q1);                       \
        const unsigned wbyte = ((ufix >> 7) & ~3u)                            \
                             + ((ufix & 256u) ? 4288u : 0u)  /* Ho base B */  \
                             + (unsigned)rowbyte;                             \
        atomicAdd((unsigned*)((char*)Ls + wbyte), val);                       \
    }

    // ---- phase 1: CIC deposit; full 128-node chunks guard-free + tail ----
    {
        const int len = s1 - s0;
        const int nfull = len >> 7;
        int base = s0;
        for (int c = 0; c < nfull; ++c, base += 128) {
            float xs[4][3];
#pragma unroll
            for (int k = 0; k < 4; ++k) {
                const float3 xx = *(const float3*)(x + 3 * (size_t)(base + (k << 5) + slot));
                xs[k][0] = xx.x; xs[k][1] = xx.y; xs[k][2] = xx.z;
            }
#pragma unroll
            for (int k = 0; k < 4; ++k) DEPOSIT(xs[k][0], xs[k][1], xs[k][2]);
        }
        for (; base < s1; base += 32) {
            const int idx = base + slot;
            if (idx < s1) {
                const float3 xx = *(const float3*)(x + 3 * (size_t)idx);
                DEPOSIT(xx.x, xx.y, xx.z);
            }
        }
    }

    __syncthreads();                             // barrier 2: deposits done

    // ---- per-wave rows 2wv, 2wv+1: reconstruct -> scan -> (barrier) conv ----
    // H[a] = He.half[a] + Ho.half[a-1]:
    //   a even: He[a>>1].lo + (a>0 ? Ho[(a>>1)-1].hi : 0)
    //   a odd : Ho[a>>1].lo + He[a>>1].hi
    float win[2];
    {
        const int par = lane & 1;
#pragma unroll
        for (int rr = 0; rr < 2; ++rr) {
            const int row = 2 * wv + rr;
            const unsigned* He = Ls + row * ROWW;
            const unsigned* Ho = Ls + HO_BASEW + row * ROWW;
            float* Hf = (float*)(Ls + HF_BASEW) + row * ROW32;
            float c0, c1, c2, c3;
            {
                unsigned heW, he, ho;
                // q = 0
                heW = He[lane >> 1];
                he  = par ? (heW >> 16) : (heW & 0xFFFFu);
                ho  = 0u;
                if (lane > 0) {
                    const unsigned hoW = Ho[(lane - 1) >> 1];
                    ho = par ? (hoW & 0xFFFFu) : (hoW >> 16);
                }
                c0 = (float)(he + ho);
                // q = 1..3 (a = lane + 64q > 0 always)
                const int a1 = lane + 64, a2 = lane + 128, a3 = lane + 192;
                heW = He[a1 >> 1]; he = par ? (heW >> 16) : (heW & 0xFFFFu);
                { const unsigned hoW = Ho[(a1 - 1) >> 1];
                  ho = par ? (hoW & 0xFFFFu) : (hoW >> 16); }
                c1 = (float)(he + ho); Hf[a1] = c1;
                heW = He[a2 >> 1]; he = par ? (heW >> 16) : (heW & 0xFFFFu);
                { const unsigned hoW = Ho[(a2 - 1) >> 1];
                  ho = par ? (hoW & 0xFFFFu) : (hoW >> 16); }
                c2 = (float)(he + ho); Hf[a2] = c2;
                heW = He[a3 >> 1]; he = par ? (heW >> 16) : (heW & 0xFFFFu);
                { const unsigned hoW = Ho[(a3 - 1) >> 1];
                  ho = par ? (hoW & 0xFFFFu) : (hoW >> 16); }
                c3 = (float)(he + ho); Hf[a3] = c3;
            }
            // register suffix scan; 64-tap saturated window in-register
            float tot23 = c2 + c3;
#pragma unroll
            for (int d = 1; d < 64; d <<= 1) tot23 += __shfl_xor(tot23, d, 64);
            const float s1v   = wave_suffix(c1, lane) + tot23;
            const float carry = __shfl(s1v, 0, 64);
            const float s0v   = wave_suffix(c0, lane) + carry;
            win[rr] = (s0v - s1v) * (1.0f / 256.0f);
        }
    }

    __syncthreads();   // barrier 3: Hf visible to cross-lane conv reads

    // ---- phase 2: conv, 80 literal-fma taps per row, 40 ds_read2 ----
#pragma unroll
    for (int rr = 0; rr < 2; ++rr) {
        const int row = 2 * wv + rr;
        const float* H = (const float*)(Ls + HF_BASEW) + row * ROW32 + lane;
        float a0 = win[rr], a1 = 0.f;
#pragma unroll
        for (int j = J0; j < STEPS; j += 2) {
            a0 = fmaf(WT.w[j],     H[j],     a0);
            a1 = fmaf(WT.w[j + 1], H[j + 1], a1);
        }
        out[((size_t)b * 64 + tbase + row) * 64 + lane] = a0 + a1;
    }
#undef DEPOSIT
}

extern "C" void kernel_launch(void* const* d_in, const int* in_sizes, int n_in,
                              void* d_out, int out_size, void* d_ws, size_t ws_size,
                              hipStream_t stream) {
    const float* x     = (const float*)d_in[0];
    const float* v     = (const float*)d_in[1];
    const int*   batch = (const int*)d_in[2];
    float*       out   = (float*)d_out;

    const int n = in_sizes[0] / 3;

    const double d = 2.2 / 63.0;
    const float inv_d256 = (float)(256.0 / d);         // bin scale 256
    const float bias256  = (79.5f + 63.0f) * 256.0f;   // 36480: pad included

    hipLaunchKernelGGL(ect_fused13_kernel, dim3(BSEG * TQ), dim3(THREADS), 0,
                       stream, x, v, batch, out, n, inv_d256, bias256);
}